// Round 11
// baseline (21.919 us; speedup 1.0000x reference)
//
#include <hip/hip_runtime.h>
#include <hip/hip_fp16.h>

// NEAT sparse MLP fwd. LAYER_SIZES=[256,512,512,512,512,64], FAN_IN=32, BATCH=2048.
// OFFSETS=[0,256,768,1280,1792,2304,2368]; E_TOT=67584.
//
// R11: SINGLE kernel. The edge-record transpose (pack) is fused into fwd:
// each thread register-prefetches 8 coalesced raw quads of the NEXT layer
// during the current layer's compute (R8's cross-barrier prefetch), packs
// them to 4 B records (local_off*16 | w_f16<<16), and ds_writes them into a
// padded LDS record buffer (node stride 9 quads -> 2-way bank aliasing on
// both write and read = free). Layer-5 raw quads are already thread-aligned
// (quad 16384+tid) -> registers directly. Acts f16 [node][8] in LDS; one
// ds_read_b128 per edge feeds 8 batch rows. grid=256, 512 thr, 88 KB LDS.

typedef _Float16 half8_t  __attribute__((ext_vector_type(8)));
typedef float    float8_t __attribute__((ext_vector_type(8)));

constexpr int TB    = 8;
constexpr int BLOCK = 512;

__device__ __forceinline__ float sigmoidf(float s)
{
    return __fdividef(1.0f, 1.0f + __expf(-s));
}

__device__ __forceinline__ unsigned packrec(int s, int offPrev, float wf)
{
    return ((unsigned)(s - offPrev) * 16u) |
           ((unsigned)__half_as_ushort(__float2half(wf)) << 16);
}

__global__ __launch_bounds__(BLOCK) void neat_fwd(
    const float* __restrict__ x,
    const float* __restrict__ w,
    const int*   __restrict__ src,
    float*       __restrict__ out)
{
    // padded record buffer: quad q lives at q + (q>>3)  (max 4095+511=4606)
    __shared__ __align__(16) uint4    recbuf[4608];     // 72 KB
    __shared__ __align__(16) _Float16 bufA[512 * TB];   // 8 KB
    __shared__ __align__(16) _Float16 bufB[512 * TB];   // 8 KB

    const int tid    = threadIdx.x;
    const int batch0 = blockIdx.x * TB;
    const int4*   s4p = (const int4*)src;
    const float4* w4p = (const float4*)w;

    // write base for this thread's staged quads: padidx(tid) ; k adds 576
    const int wbase = tid + (tid >> 3);

    // ---- prologue: prefetch layer-1 records, coalesced ----
    int4 rS[8]; float4 rW[8];
#pragma unroll
    for (int k = 0; k < 8; ++k) { rS[k] = s4p[tid + k * 512]; rW[k] = w4p[tid + k * 512]; }

    // stage input acts as f16 [node][8]
    {
        const int r  = tid >> 6;
        const int c4 = (tid & 63) * 4;
        const float4 v = *(const float4*)(x + (size_t)(batch0 + r) * 256 + c4);
        bufA[(c4 + 0) * TB + r] = (_Float16)v.x;
        bufA[(c4 + 1) * TB + r] = (_Float16)v.y;
        bufA[(c4 + 2) * TB + r] = (_Float16)v.z;
        bufA[(c4 + 3) * TB + r] = (_Float16)v.w;
    }

    // pack + stage layer-1 records (offPrev = 0)
#pragma unroll
    for (int k = 0; k < 8; ++k) {
        uint4 pr;
        pr.x = packrec(rS[k].x, 0, rW[k].x);
        pr.y = packrec(rS[k].y, 0, rW[k].y);
        pr.z = packrec(rS[k].z, 0, rW[k].z);
        pr.w = packrec(rS[k].w, 0, rW[k].w);
        recbuf[wbase + k * 576] = pr;
    }
    __syncthreads();

    _Float16* prev = bufA;
    _Float16* cur  = bufB;
    int4 s5; float4 w5;

#define EDGE(RR)                                                               \
    do {                                                                       \
        const unsigned rr = (unsigned)(RR);                                    \
        const float wf = __half2float(__ushort_as_half((unsigned short)(rr >> 16))); \
        const half8_t a = *(const half8_t*)(pv + (rr & 0xffffu));              \
        _Pragma("unroll")                                                      \
        for (int k = 0; k < 8; ++k)                                            \
            acc[k] = fmaf((float)a[k], wf, acc[k]);                            \
    } while (0)

    // Layers 1..4 (512 nodes each): thread == node.
#pragma unroll
    for (int l = 0; l < 4; ++l) {
        // Issue NEXT layer's record loads first; they fly under this layer's
        // compute and across the barrier.
        if (l < 3) {
            const int gb = (l + 1) * 4096 + tid;
#pragma unroll
            for (int k = 0; k < 8; ++k) { rS[k] = s4p[gb + k * 512]; rW[k] = w4p[gb + k * 512]; }
        } else {
            s5 = s4p[16384 + tid]; w5 = w4p[16384 + tid];
        }

        const char* pv = (const char*)prev;
        float8_t acc = {0.f, 0.f, 0.f, 0.f, 0.f, 0.f, 0.f, 0.f};
#pragma unroll
        for (int c = 0; c < 8; ++c) {
            const uint4 r4 = recbuf[tid * 9 + c];
            EDGE(r4.x);
            EDGE(r4.y);
            EDGE(r4.z);
            EDGE(r4.w);
        }

        half8_t r;
#pragma unroll
        for (int k = 0; k < 8; ++k)
            r[k] = (_Float16)sigmoidf(acc[k]);
        *(half8_t*)(cur + tid * TB) = r;
        __syncthreads();   // recbuf readers done; cur acts visible

        if (l < 3) {
            const int offPrevNext = 256 + l * 512;   // offPrev of layer l+2's source
#pragma unroll
            for (int k = 0; k < 8; ++k) {
                uint4 pr;
                pr.x = packrec(rS[k].x, offPrevNext, rW[k].x);
                pr.y = packrec(rS[k].y, offPrevNext, rW[k].y);
                pr.z = packrec(rS[k].z, offPrevNext, rW[k].z);
                pr.w = packrec(rS[k].w, offPrevNext, rW[k].w);
                recbuf[wbase + k * 576] = pr;
            }
            __syncthreads();   // new records visible
        }

        _Float16* t = prev; prev = cur; cur = t;
    }

    // Layer 5: 64 nodes x 32 edges. Thread tid: n = tid>>3, c = tid&7 owns
    // raw quad 16384+tid (already in s5/w5). 8 partials per node live in 8
    // consecutive lanes -> __shfl_xor reduce. offPrev=1792 folded into pv.
    {
        const char* pv = (const char*)prev - (1792 * 16);
        float8_t acc = {0.f, 0.f, 0.f, 0.f, 0.f, 0.f, 0.f, 0.f};
        {
            const float wfx = w5.x, wfy = w5.y, wfz = w5.z, wfw = w5.w;
            const half8_t a0 = *(const half8_t*)(pv + ((unsigned)s5.x * 16u));
            const half8_t a1 = *(const half8_t*)(pv + ((unsigned)s5.y * 16u));
            const half8_t a2 = *(const half8_t*)(pv + ((unsigned)s5.z * 16u));
            const half8_t a3 = *(const half8_t*)(pv + ((unsigned)s5.w * 16u));
#pragma unroll
            for (int k = 0; k < 8; ++k) acc[k] = fmaf((float)a0[k], wfx, acc[k]);
#pragma unroll
            for (int k = 0; k < 8; ++k) acc[k] = fmaf((float)a1[k], wfy, acc[k]);
#pragma unroll
            for (int k = 0; k < 8; ++k) acc[k] = fmaf((float)a2[k], wfz, acc[k]);
#pragma unroll
            for (int k = 0; k < 8; ++k) acc[k] = fmaf((float)a3[k], wfw, acc[k]);
        }
#pragma unroll
        for (int m = 1; m <= 4; m <<= 1) {
#pragma unroll
            for (int k = 0; k < 8; ++k)
                acc[k] += __shfl_xor(acc[k], m, 64);
        }
        if ((tid & 7) == 0) {
            const int n = tid >> 3;
#pragma unroll
            for (int b = 0; b < 8; ++b)
                out[(size_t)(batch0 + b) * 64 + n] = sigmoidf(acc[b]);
        }
    }
#undef EDGE
}

extern "C" void kernel_launch(void* const* d_in, const int* in_sizes, int n_in,
                              void* d_out, int out_size, void* d_ws, size_t ws_size,
                              hipStream_t stream)
{
    const float* x   = (const float*)d_in[0];
    const float* w   = (const float*)d_in[1];
    const int*   src = (const int*)d_in[2];
    float* out = (float*)d_out;

    const int batch = in_sizes[0] / 256;   // 2048
    const int grid  = batch / TB;          // 256

    neat_fwd<<<grid, BLOCK, 0, stream>>>(x, w, src, out);
}

// Round 12
// 20.934 us; speedup vs baseline: 1.0471x; 1.0471x over previous
//
#include <hip/hip_runtime.h>
#include <hip/hip_fp16.h>

// NEAT sparse MLP fwd. LAYER_SIZES=[256,512,512,512,512,64], FAN_IN=32, BATCH=2048.
// OFFSETS=[0,256,768,1280,1792,2304,2368]; E_TOT=67584.
//
// R12 = R8 (best measured: 20.98 us), reverted after R9-R11 probes.
// Structure: pack kernel transposes edges into 4 B records
// (local_src*16 | w_f16<<16), chunk-transposed per 64-node wave group so wave
// record loads are coalesced; fwd stages acts as f16 [node][8] in LDS (one
// ds_read_b128 per edge feeds 8 batch rows), cross-barrier register prefetch
// of next layer's records, layer-5 via 8-lane __shfl_xor reduce.
// grid=256 (1 block/CU), 512 threads.

typedef _Float16 half8_t  __attribute__((ext_vector_type(8)));
typedef float    float8_t __attribute__((ext_vector_type(8)));

constexpr int TB    = 8;
constexpr int BLOCK = 512;
constexpr int E_TOT = 67584;

__global__ __launch_bounds__(256) void pack_edges(const int* __restrict__ src,
                                                  const float* __restrict__ w,
                                                  unsigned* __restrict__ rec)
{
    const int o = blockIdx.x * 256 + threadIdx.x;
    if (o >= E_TOT) return;
    int eid, offPrev;
    if (o < 65536) {
        // 512-wide layers: word idx ol = (((g*8 + c)*64 + i)*4 + q)
        // covers eid = e0 + (g*64+i)*32 + c*4 + q.
        const int layer = o >> 14;
        const int e0    = layer << 14;
        offPrev = (layer == 0) ? 0 : (256 + (layer - 1) * 512);
        const int ol = o - e0;
        const int q = ol & 3, t = ol >> 2;
        const int i = t & 63, c = (t >> 6) & 7, g = t >> 9;
        eid = e0 + (g * 64 + i) * 32 + c * 4 + q;
    } else {
        // layer 5: identity (raw order is already (n*8+c) record-major).
        offPrev = 1792;
        eid = o;
    }
    const unsigned off = (unsigned)(src[eid] - offPrev) * 16u;  // byte off, [node][8] f16
    const unsigned hw  = (unsigned)__half_as_ushort(__float2half(w[eid]));
    rec[o] = off | (hw << 16);
}

__device__ __forceinline__ float sigmoidf(float s)
{
    return __fdividef(1.0f, 1.0f + __expf(-s));
}

template<bool PACKED>
__global__ __launch_bounds__(BLOCK) void neat_fwd(
    const float* __restrict__ x,
    const float* __restrict__ w,
    const int*   __restrict__ src,
    const int4*  __restrict__ rp,      // packed records as int4 (4 edges)
    float*       __restrict__ out)
{
    __shared__ __align__(16) _Float16 bufA[512 * TB];
    __shared__ __align__(16) _Float16 bufB[512 * TB];

    const int tid    = threadIdx.x;
    const int batch0 = blockIdx.x * TB;
    const int base   = (tid >> 6) * 512 + (tid & 63);

    int4 rcur[8], rnxt[8];
    if (PACKED) {
#pragma unroll
        for (int c = 0; c < 8; ++c) rcur[c] = rp[base + c * 64];
    }

    {
        const int r  = tid >> 6;
        const int c4 = (tid & 63) * 4;
        const float4 v = *(const float4*)(x + (size_t)(batch0 + r) * 256 + c4);
        bufA[(c4 + 0) * TB + r] = (_Float16)v.x;
        bufA[(c4 + 1) * TB + r] = (_Float16)v.y;
        bufA[(c4 + 2) * TB + r] = (_Float16)v.z;
        bufA[(c4 + 3) * TB + r] = (_Float16)v.w;
    }
    __syncthreads();

    _Float16* prev = bufA;
    _Float16* cur  = bufB;

#define EDGE(RR, ACC)                                                          \
    do {                                                                       \
        const unsigned rr = (unsigned)(RR);                                    \
        const float wf = __half2float(__ushort_as_half((unsigned short)(rr >> 16))); \
        const half8_t a = *(const half8_t*)(pv + (rr & 0xffffu));              \
        _Pragma("unroll")                                                      \
        for (int k = 0; k < 8; ++k)                                            \
            ACC[k] = fmaf((float)a[k], wf, ACC[k]);                            \
    } while (0)

#define EDGE_RAW(SRCID, WF, ACC)                                               \
    do {                                                                       \
        const float wf = (WF);                                                 \
        const half8_t a = *(const half8_t*)(pv + (unsigned)((SRCID) - offPrev) * 16u); \
        _Pragma("unroll")                                                      \
        for (int k = 0; k < 8; ++k)                                            \
            ACC[k] = fmaf((float)a[k], wf, ACC[k]);                            \
    } while (0)

    // Layers 1..4 (512 nodes each): thread == node.
#pragma unroll
    for (int l = 0; l < 4; ++l) {
        // Issue next layer's record loads first: they fly under this layer's
        // gather+FMA work and across the barrier the compiler can't cross.
        if (PACKED) {
            if (l < 3) {
                const int4* rn = rp + (l + 1) * 4096;
#pragma unroll
                for (int c = 0; c < 8; ++c) rnxt[c] = rn[base + c * 64];
            } else {
                rnxt[0] = rp[16384 + tid];   // layer-5 record (identity layout)
            }
        }

        const char* pv = (const char*)prev;
        float8_t acc = {0.f, 0.f, 0.f, 0.f, 0.f, 0.f, 0.f, 0.f};
        if (PACKED) {
#pragma unroll
            for (int c = 0; c < 8; ++c) {
                const int4 r4 = rcur[c];
                EDGE(r4.x, acc);
                EDGE(r4.y, acc);
                EDGE(r4.z, acc);
                EDGE(r4.w, acc);
            }
        } else {
            const int e0 = l * 16384;
            const int offPrev = (l == 0) ? 0 : (256 + (l - 1) * 512);
            const int ebase = e0 + tid * 32;
#pragma unroll
            for (int c = 0; c < 8; ++c) {
                const int4   s4 = *(const int4*)(src + ebase + c * 4);
                const float4 w4 = *(const float4*)(w + ebase + c * 4);
                EDGE_RAW(s4.x, w4.x, acc);
                EDGE_RAW(s4.y, w4.y, acc);
                EDGE_RAW(s4.z, w4.z, acc);
                EDGE_RAW(s4.w, w4.w, acc);
            }
        }

        half8_t r;
#pragma unroll
        for (int k = 0; k < 8; ++k)
            r[k] = (_Float16)sigmoidf(acc[k]);
        *(half8_t*)(cur + tid * TB) = r;
        __syncthreads();
        _Float16* t = prev; prev = cur; cur = t;

        if (PACKED) {
#pragma unroll
            for (int c = 0; c < 8; ++c) rcur[c] = rnxt[c];
        }
    }

    // Layer 5: 64 nodes x 32 edges. Thread tid: n = tid>>3, c = tid&7 handles
    // 4 edges; the 8 partials of a node live in 8 consecutive lanes ->
    // __shfl_xor reduce, no LDS scratch, no extra barrier.
    {
        const char* pv = (const char*)prev;
        float8_t acc = {0.f, 0.f, 0.f, 0.f, 0.f, 0.f, 0.f, 0.f};
        if (PACKED) {
            const int4 r4 = rcur[0];
            EDGE(r4.x, acc);
            EDGE(r4.y, acc);
            EDGE(r4.z, acc);
            EDGE(r4.w, acc);
        } else {
            const int offPrev = 1792;
            const int eb = 65536 + tid * 4;
            const int4   s4 = *(const int4*)(src + eb);
            const float4 w4 = *(const float4*)(w + eb);
            EDGE_RAW(s4.x, w4.x, acc);
            EDGE_RAW(s4.y, w4.y, acc);
            EDGE_RAW(s4.z, w4.z, acc);
            EDGE_RAW(s4.w, w4.w, acc);
        }
#pragma unroll
        for (int m = 1; m <= 4; m <<= 1) {
#pragma unroll
            for (int k = 0; k < 8; ++k)
                acc[k] += __shfl_xor(acc[k], m, 64);
        }
        if ((tid & 7) == 0) {
            const int n = tid >> 3;
#pragma unroll
            for (int b = 0; b < 8; ++b)
                out[(size_t)(batch0 + b) * 64 + n] = sigmoidf(acc[b]);
        }
    }
#undef EDGE
#undef EDGE_RAW
}

extern "C" void kernel_launch(void* const* d_in, const int* in_sizes, int n_in,
                              void* d_out, int out_size, void* d_ws, size_t ws_size,
                              hipStream_t stream)
{
    const float* x   = (const float*)d_in[0];
    const float* w   = (const float*)d_in[1];
    const int*   src = (const int*)d_in[2];
    float* out = (float*)d_out;

    const int batch = in_sizes[0] / 256;   // 2048
    const int grid  = batch / TB;          // 256

    unsigned* rec = (unsigned*)d_ws;

    if (ws_size >= (size_t)E_TOT * 4) {
        pack_edges<<<(E_TOT + 255) / 256, 256, 0, stream>>>(src, w, rec);
        neat_fwd<true><<<grid, BLOCK, 0, stream>>>(x, w, src, (const int4*)rec, out);
    } else {
        neat_fwd<false><<<grid, BLOCK, 0, stream>>>(x, w, src, (const int4*)rec, out);
    }
}